// Round 5
// baseline (194.578 us; speedup 1.0000x reference)
//
#include <hip/hip_runtime.h>
#include <stdint.h>

typedef __attribute__((ext_vector_type(4))) float f32x4;
typedef __attribute__((ext_vector_type(8))) short s16x8;

#define BB 4
#define NN 4096
#define FF 32
#define BNF (BB*NN*FF)   // 524288

typedef __attribute__((address_space(3))) void       as3_void;
typedef const __attribute__((address_space(1))) void as1_cvoid;

// ---------- bf16 helpers ----------
static __device__ __forceinline__ float bf2f(uint16_t u) {
    union { uint32_t i; float f; } v; v.i = ((uint32_t)u) << 16; return v.f;
}
static __device__ __forceinline__ uint16_t f2bf(float f) {
    union { float f; uint32_t i; } v; v.f = f;
    uint32_t r = v.i + 0x7FFFu + ((v.i >> 16) & 1u);
    return (uint16_t)(r >> 16);
}
static __device__ __forceinline__ float sig_acc(float x) { return 1.0f / (1.0f + expf(-x)); }

// ======================================================================
// prep: ONE launch for all input-only work.
//   blocks [0, cvtN):            adj fp32 -> bf16            (cvtN = 8192 or 0)
//   blocks [cvtN, cvtN+112):     pack W  -> Wp (MFMA B-frag layout, swizzled)
//   blocks [cvtN+112, +768):     pack x,h -> P rows 0..255; m -> P2 rows 128..255
// ======================================================================
__global__ __launch_bounds__(256) void prep_kernel(
    const float* __restrict__ adj, uint16_t* __restrict__ adjb, int cvtN,
    const float* __restrict__ Wf, uint16_t* __restrict__ Wp,
    const float* __restrict__ x, const float* __restrict__ h,
    const float* __restrict__ m,
    uint16_t* __restrict__ P, uint16_t* __restrict__ P2)
{
    int bid = blockIdx.x;
    int t = threadIdx.x;

    if (bid < cvtN) {
        size_t i = ((size_t)bid * 256 + t) * 8;
        float4 v0 = *(const float4*)(adj + i);
        float4 v1 = *(const float4*)(adj + i + 4);
        union { uint4 u; uint16_t e[8]; } o;
        o.e[0] = f2bf(v0.x); o.e[1] = f2bf(v0.y); o.e[2] = f2bf(v0.z); o.e[3] = f2bf(v0.w);
        o.e[4] = f2bf(v1.x); o.e[5] = f2bf(v1.y); o.e[6] = f2bf(v1.z); o.e[7] = f2bf(v1.w);
        *(uint4*)(adjb + i) = o.u;
        return;
    }
    bid -= cvtN;

    if (bid < 112) {
        // W: fp32 [14][32][64] -> bf16 Wp[gp][col][slot^swz][k&7]
        // B-frag (16x16x32): lane l holds B[k=(l>>4)*8+e][col=l&15].
        int idx = bid * 256 + t;                    // 14*32*64 = 28672
        int g   = idx >> 11;
        int k   = (idx >> 6) & 31;
        int col = idx & 63;
        uint16_t v = f2bf(Wf[idx]);                 // Wf[g][k][col]
        int gp = g >> 1;
        int sl = ((g & 1) << 2) | (k >> 3);
        int ph = sl ^ (col & 7);
        Wp[((gp * 64 + col) * 64) + ph * 8 + (k & 7)] = v;
        return;
    }
    bid -= 112;

    // pack: state [B][N][F] fp32 -> dst[rowbase + b*32 + f][n] bf16
    const float* src; uint16_t* dst; int rowbase, b, n0;
    if (bid < 512) {
        int tensor = bid >> 8;
        src = tensor ? h : x; dst = P; rowbase = tensor * 128;
        b = (bid >> 6) & 3; n0 = (bid & 63) * 64;
    } else {
        int q = bid - 512;
        src = m; dst = P2; rowbase = 128;
        b = q >> 6; n0 = (q & 63) * 64;
    }
    __shared__ uint16_t tl[32][65];
    {
        int i = t >> 2, ch = t & 3;       // node i (0..63), f-chunk ch (8 floats)
        size_t idx = ((size_t)(b * NN + n0 + i)) * FF + ch * 8;
        float4 v0 = *(const float4*)(src + idx);
        float4 v1 = *(const float4*)(src + idx + 4);
        uint16_t e[8] = { f2bf(v0.x), f2bf(v0.y), f2bf(v0.z), f2bf(v0.w),
                          f2bf(v1.x), f2bf(v1.y), f2bf(v1.z), f2bf(v1.w) };
        #pragma unroll
        for (int k = 0; k < 8; k++) tl[ch * 8 + k][i] = e[k];
    }
    __syncthreads();
    {
        int f = t >> 3, ch = t & 7;
        union { uint4 u; uint16_t e[8]; } v;
        #pragma unroll
        for (int k = 0; k < 8; k++) v.e[k] = tl[f][ch * 8 + k];
        size_t row = (size_t)(rowbase + b * 32 + f);
        *(uint4*)(dst + row * NN + n0 + ch * 8) = v.u;
    }
}

// ---------- GEMM: out[c][m] = sum_k adj[m][k] * Bt[c][k]; C fixed = 256 ----------
// 128x128 tile, BK=32, 4 waves (2x2 of 64x64), 16x16x32 bf16 MFMA.
// LDS tile rows are 64B = 4 16B slots; phys_slot = logical_slot ^ ((row>>1)&3).
// bf16 path stages via global_load_lds width=16 (no VGPR round-trip).
__global__ __launch_bounds__(256) void gemm_kernel(
    const void* __restrict__ Av,      // adj: bf16 (isf32A=0) or fp32 (isf32A=1)
    const uint16_t* __restrict__ Bt,  // [256][4096] bf16
    float* __restrict__ part, uint16_t* __restrict__ Cb,
    int kLen, int direct, int isf32A)
{
    int mt = blockIdx.x, nt = blockIdx.y, ks = blockIdx.z;
    int m0 = mt * 128, c0 = nt * 128, k0 = ks * kLen;
    __shared__ __align__(16) uint16_t aL[128 * 32];
    __shared__ __align__(16) uint16_t bL[128 * 32];
    int t = threadIdx.x;
    int lane = t & 63, w = t >> 6;
    int wm = (w & 1) * 64, wn = (w >> 1) * 64;
    int lm = lane & 15, lk = lane >> 4;

    const uint16_t* A16 = (const uint16_t*)Av;
    const float*    Af  = (const float*)Av;

    f32x4 acc[4][4] = {};

    for (int kk = k0; kk < k0 + kLen; kk += 32) {
        if (!isf32A) {
            #pragma unroll
            for (int q = 0; q < 2; q++) {
                int pos  = q * 4096 + t * 16;            // byte offset into 8KB tile
                int row  = pos >> 6;                     // 64 B per tile row
                int slot = ((pos >> 4) & 3) ^ ((row >> 1) & 3);
                int col  = slot * 8;                     // bf16 element within row
                size_t aidx = (size_t)(m0 + row) * 4096 + kk + col;
                size_t bidx = (size_t)(c0 + row) * 4096 + kk + col;
                __builtin_amdgcn_global_load_lds((as1_cvoid*)(A16 + aidx),
                                                 (as3_void*)((char*)aL + pos), 16, 0, 0);
                __builtin_amdgcn_global_load_lds((as1_cvoid*)(Bt + bidx),
                                                 (as3_void*)((char*)bL + pos), 16, 0, 0);
            }
        } else {
            union { uint4 u; uint16_t e[8]; } sa[2], sb[2];
            #pragma unroll
            for (int q = 0; q < 2; q++) {
                int pos  = q * 4096 + t * 16;
                int row  = pos >> 6;
                int slot = ((pos >> 4) & 3) ^ ((row >> 1) & 3);
                int col  = slot * 8;
                size_t aidx = (size_t)(m0 + row) * 4096 + kk + col;
                size_t bidx = (size_t)(c0 + row) * 4096 + kk + col;
                union { uint4 u[2]; float f[8]; } va;
                va.u[0] = *(const uint4*)(Af + aidx);
                va.u[1] = *(const uint4*)(Af + aidx + 4);
                #pragma unroll
                for (int k = 0; k < 8; k++) sa[q].e[k] = f2bf(va.f[k]);
                sb[q].u = *(const uint4*)(Bt + bidx);
            }
            #pragma unroll
            for (int q = 0; q < 2; q++) {
                int pos = q * 4096 + t * 16;
                *(uint4*)((char*)aL + pos) = sa[q].u;
                *(uint4*)((char*)bL + pos) = sb[q].u;
            }
        }
        __syncthreads();
        s16x8 af[4], bfr[4];
        #pragma unroll
        for (int i = 0; i < 4; i++) {
            int r = wm + i * 16 + lm;
            af[i] = *(const s16x8*)(aL + r * 32 + ((lk ^ ((r >> 1) & 3)) * 8));
        }
        #pragma unroll
        for (int j = 0; j < 4; j++) {
            int r = wn + j * 16 + lm;
            bfr[j] = *(const s16x8*)(bL + r * 32 + ((lk ^ ((r >> 1) & 3)) * 8));
        }
        #pragma unroll
        for (int i = 0; i < 4; i++)
            #pragma unroll
            for (int j = 0; j < 4; j++)
                acc[i][j] = __builtin_amdgcn_mfma_f32_16x16x32_bf16(af[i], bfr[j], acc[i][j], 0, 0, 0);
        __syncthreads();
    }

    // C/D layout: col=lane&15 (c dim), row=(lane>>4)*4+reg (m dim)
    int r4 = (lane >> 4) * 4;
    if (direct) {
        #pragma unroll
        for (int i = 0; i < 4; i++)
            #pragma unroll
            for (int j = 0; j < 4; j++) {
                int c = c0 + wn + j * 16 + lm;
                int mr = m0 + wm + i * 16 + r4;
                union { uint2 u; uint16_t e[4]; } v;
                #pragma unroll
                for (int r = 0; r < 4; r++) v.e[r] = f2bf(acc[i][j][r]);
                *(uint2*)(Cb + (size_t)c * 4096 + mr) = v.u;
            }
    } else {
        #pragma unroll
        for (int i = 0; i < 4; i++)
            #pragma unroll
            for (int j = 0; j < 4; j++) {
                int c = c0 + wn + j * 16 + lm;
                int mr = m0 + wm + i * 16 + r4;
                *(f32x4*)(part + ((size_t)ks * 256 + c) * 4096 + mr) = acc[i][j];
            }
    }
}

// ======================================================================
// fuse1: 1024 single-wave blocks, block = (batch b, 16 nodes).
// Lane l: register split-K reduce of c'-row l x 16 nodes -> LDS transpose ->
// MFMA dense (8 gates, B-frags direct from global Wp, L2-broadcast) ->
// GLU + LSTM -> c_new + h1 packed to P2.
// ======================================================================
__global__ __launch_bounds__(64) void fuse1_kernel(
    const float* __restrict__ part,   // [ns][256][4096] fp32 (ns>0)
    const uint16_t* __restrict__ Cbi, // [256][4096] bf16 (ns==0)
    const uint16_t* __restrict__ Wp,  // packed W (prep)
    const float* __restrict__ bf_,
    const float* __restrict__ cf,
    float* __restrict__ cnew, uint16_t* __restrict__ S2t, int ns)
{
    __shared__ float    AL[64 * 17];   // [c'=f(0..31)=ax,(32..63)=ah][node], pitch 17
    __shared__ uint16_t H1[32 * 18];   // [f][node]

    int l = threadIdx.x;               // 0..63
    int bid = blockIdx.x;              // 1024
    int b = bid >> 8, n0 = (bid & 255) * 16;
    int j = l & 15, kg = l >> 4, r4 = kg * 4;

    // c prefetch (in flight under the reduce)
    float cv[2][4];
    #pragma unroll
    for (int hh = 0; hh < 2; hh++)
        #pragma unroll
        for (int r = 0; r < 4; r++)
            cv[hh][r] = cf[((size_t)(b * NN + n0 + r4 + r)) * FF + j + hh * 16];

    // lane l owns c'-row l (f index; 0..31 ax, 32..63 ah), nodes n0..n0+15
    int crow = (l < 32) ? (b * 32 + l) : (128 + b * 32 + (l - 32));

    if (ns) {
        const float* gp = part + (size_t)crow * 4096 + n0;
        f32x4 c0 = *(const f32x4*)(gp);
        f32x4 c1 = *(const f32x4*)(gp + 4);
        f32x4 c2 = *(const f32x4*)(gp + 8);
        f32x4 c3 = *(const f32x4*)(gp + 12);
        f32x4 s0 = {}, s1 = {}, s2 = {}, s3 = {};
        for (int ks = 0; ks < ns; ks++) {
            f32x4 nv0, nv1, nv2, nv3;
            if (ks + 1 < ns) {
                const float* np = gp + (size_t)(ks + 1) * (256 * 4096);
                nv0 = *(const f32x4*)(np);
                nv1 = *(const f32x4*)(np + 4);
                nv2 = *(const f32x4*)(np + 8);
                nv3 = *(const f32x4*)(np + 12);
            }
            s0 += c0; s1 += c1; s2 += c2; s3 += c3;
            if (ks + 1 < ns) { c0 = nv0; c1 = nv1; c2 = nv2; c3 = nv3; }
        }
        #pragma unroll
        for (int e = 0; e < 4; e++) {
            AL[l * 17 + e]      = s0[e];
            AL[l * 17 + 4 + e]  = s1[e];
            AL[l * 17 + 8 + e]  = s2[e];
            AL[l * 17 + 12 + e] = s3[e];
        }
    } else {
        const uint16_t* cp = Cbi + (size_t)crow * 4096 + n0;
        union { uint4 u; uint16_t e[8]; } v0, v1;
        v0.u = *(const uint4*)(cp);
        v1.u = *(const uint4*)(cp + 8);
        #pragma unroll
        for (int k = 0; k < 8; k++) {
            AL[l * 17 + k]     = bf2f(v0.e[k]);
            AL[l * 17 + 8 + k] = bf2f(v1.e[k]);
        }
    }
    __syncthreads();

    // A fragments: lane l holds A[node = l&15][k = (l>>4)*8 + e]
    s16x8 a_ax, a_ah;
    #pragma unroll
    for (int e = 0; e < 8; e++) {
        int k = kg * 8 + e;
        a_ax[e] = (short)f2bf(AL[k * 17 + j]);
        a_ah[e] = (short)f2bf(AL[(32 + k) * 17 + j]);
    }

    float s[4][2][4];
    #pragma unroll
    for (int p = 0; p < 4; p++) {
        int g0 = p * 2, g1 = p * 2 + 1;          // even: ax, odd: ah
        f32x4 ac0[4] = {}, ac1[4] = {};
        #pragma unroll
        for (int ct = 0; ct < 4; ct++) {
            int col = ct * 16 + j;
            int ph0 = (kg)     ^ (col & 7);
            int ph1 = (4 + kg) ^ (col & 7);
            s16x8 b0 = *(const s16x8*)(Wp + (p * 64 + col) * 64 + ph0 * 8);
            s16x8 b1 = *(const s16x8*)(Wp + (p * 64 + col) * 64 + ph1 * 8);
            ac0[ct] = __builtin_amdgcn_mfma_f32_16x16x32_bf16(a_ax, b0, ac0[ct], 0, 0, 0);
            ac1[ct] = __builtin_amdgcn_mfma_f32_16x16x32_bf16(a_ah, b1, ac1[ct], 0, 0, 0);
        }
        // GLU: cols (hh*16+j) pair with (32+hh*16+j) -> both live in this lane
        #pragma unroll
        for (int hh = 0; hh < 2; hh++)
            #pragma unroll
            for (int r = 0; r < 4; r++) {
                float z0l = ac0[hh][r]     + bf_[g0 * 64 + hh * 16 + j];
                float z0r = ac0[2 + hh][r] + bf_[g0 * 64 + 32 + hh * 16 + j];
                float z1l = ac1[hh][r]     + bf_[g1 * 64 + hh * 16 + j];
                float z1r = ac1[2 + hh][r] + bf_[g1 * 64 + 32 + hh * 16 + j];
                s[p][hh][r] = z0l * sig_acc(z0r) + z1l * sig_acc(z1r);
            }
    }

    // LSTM update (pure elementwise in registers)
    #pragma unroll
    for (int hh = 0; hh < 2; hh++)
        #pragma unroll
        for (int r = 0; r < 4; r++) {
            size_t gidx = ((size_t)(b * NN + n0 + r4 + r)) * FF + j + hh * 16;
            float fg = sig_acc(s[0][hh][r]);
            float ig = sig_acc(s[1][hh][r]);
            float cc = tanhf(s[2][hh][r]);
            float og = sig_acc(s[3][hh][r]);
            float cn = fg * cv[hh][r] + ig * cc;
            cnew[gidx] = cn;
            H1[(j + hh * 16) * 18 + r4 + r] = f2bf(og * tanhf(cn));
        }
    __syncthreads();
    {   // pack h1 -> P2 rows b*32+f (GEMM2 B operand, rows 0..127)
        int f = l >> 1, half = l & 1;
        union { uint4 u; uint16_t e[8]; } v;
        #pragma unroll
        for (int k = 0; k < 8; k++) v.e[k] = H1[f * 18 + half * 8 + k];
        *(uint4*)(S2t + ((size_t)(b * 32 + f)) * NN + n0 + half * 8) = v.u;
    }
}

// ======================================================================
// fuse2: 1024 single-wave blocks; register reduce + MFMA dense (6 gates)
// + memory-state update.
// ======================================================================
__global__ __launch_bounds__(64) void fuse2_kernel(
    const float* __restrict__ part,
    const uint16_t* __restrict__ Cbi,
    const uint16_t* __restrict__ Wp,
    const float* __restrict__ bf_,
    const float* __restrict__ mf,
    float* __restrict__ hnew, float* __restrict__ mnew, int ns)
{
    __shared__ float AL[64 * 17];

    int l = threadIdx.x;
    int bid = blockIdx.x;
    int b = bid >> 8, n0 = (bid & 255) * 16;
    int j = l & 15, kg = l >> 4, r4 = kg * 4;

    float mv[2][4];
    #pragma unroll
    for (int hh = 0; hh < 2; hh++)
        #pragma unroll
        for (int r = 0; r < 4; r++)
            mv[hh][r] = mf[((size_t)(b * NN + n0 + r4 + r)) * FF + j + hh * 16];

    int crow = (l < 32) ? (b * 32 + l) : (128 + b * 32 + (l - 32));

    if (ns) {
        const float* gp = part + (size_t)crow * 4096 + n0;
        f32x4 c0 = *(const f32x4*)(gp);
        f32x4 c1 = *(const f32x4*)(gp + 4);
        f32x4 c2 = *(const f32x4*)(gp + 8);
        f32x4 c3 = *(const f32x4*)(gp + 12);
        f32x4 s0 = {}, s1 = {}, s2 = {}, s3 = {};
        for (int ks = 0; ks < ns; ks++) {
            f32x4 nv0, nv1, nv2, nv3;
            if (ks + 1 < ns) {
                const float* np = gp + (size_t)(ks + 1) * (256 * 4096);
                nv0 = *(const f32x4*)(np);
                nv1 = *(const f32x4*)(np + 4);
                nv2 = *(const f32x4*)(np + 8);
                nv3 = *(const f32x4*)(np + 12);
            }
            s0 += c0; s1 += c1; s2 += c2; s3 += c3;
            if (ks + 1 < ns) { c0 = nv0; c1 = nv1; c2 = nv2; c3 = nv3; }
        }
        #pragma unroll
        for (int e = 0; e < 4; e++) {
            AL[l * 17 + e]      = s0[e];
            AL[l * 17 + 4 + e]  = s1[e];
            AL[l * 17 + 8 + e]  = s2[e];
            AL[l * 17 + 12 + e] = s3[e];
        }
    } else {
        const uint16_t* cp = Cbi + (size_t)crow * 4096 + n0;
        union { uint4 u; uint16_t e[8]; } v0, v1;
        v0.u = *(const uint4*)(cp);
        v1.u = *(const uint4*)(cp + 8);
        #pragma unroll
        for (int k = 0; k < 8; k++) {
            AL[l * 17 + k]     = bf2f(v0.e[k]);
            AL[l * 17 + 8 + k] = bf2f(v1.e[k]);
        }
    }
    __syncthreads();

    s16x8 a_h1, a_m;
    #pragma unroll
    for (int e = 0; e < 8; e++) {
        int k = kg * 8 + e;
        a_h1[e] = (short)f2bf(AL[k * 17 + j]);
        a_m[e]  = (short)f2bf(AL[(32 + k) * 17 + j]);
    }

    const uint16_t* WpG = Wp + 4 * 64 * 64;   // gate-pairs 4..6 (gates 8..13)
    const float*    bG  = bf_ + 512;

    float s[3][2][4];
    #pragma unroll
    for (int p = 0; p < 3; p++) {
        int g0 = p * 2, g1 = p * 2 + 1;          // local gates; even: ah1, odd: am
        f32x4 ac0[4] = {}, ac1[4] = {};
        #pragma unroll
        for (int ct = 0; ct < 4; ct++) {
            int col = ct * 16 + j;
            int ph0 = (kg)     ^ (col & 7);
            int ph1 = (4 + kg) ^ (col & 7);
            s16x8 b0 = *(const s16x8*)(WpG + (p * 64 + col) * 64 + ph0 * 8);
            s16x8 b1 = *(const s16x8*)(WpG + (p * 64 + col) * 64 + ph1 * 8);
            ac0[ct] = __builtin_amdgcn_mfma_f32_16x16x32_bf16(a_h1, b0, ac0[ct], 0, 0, 0);
            ac1[ct] = __builtin_amdgcn_mfma_f32_16x16x32_bf16(a_m, b1, ac1[ct], 0, 0, 0);
        }
        #pragma unroll
        for (int hh = 0; hh < 2; hh++)
            #pragma unroll
            for (int r = 0; r < 4; r++) {
                float z0l = ac0[hh][r]     + bG[g0 * 64 + hh * 16 + j];
                float z0r = ac0[2 + hh][r] + bG[g0 * 64 + 32 + hh * 16 + j];
                float z1l = ac1[hh][r]     + bG[g1 * 64 + hh * 16 + j];
                float z1r = ac1[2 + hh][r] + bG[g1 * 64 + 32 + hh * 16 + j];
                s[p][hh][r] = z0l * sig_acc(z0r) + z1l * sig_acc(z1r);
            }
    }

    #pragma unroll
    for (int hh = 0; hh < 2; hh++)
        #pragma unroll
        for (int r = 0; r < 4; r++) {
            size_t gidx = ((size_t)(b * NN + n0 + r4 + r)) * FF + j + hh * 16;
            float i2 = sig_acc(s[0][hh][r]);
            float gg = sig_acc(s[1][hh][r]);
            float o2 = sig_acc(s[2][hh][r]);
            float mn = i2 * mv[hh][r] + (1.0f - i2) * gg;
            mnew[gidx] = mn;
            hnew[gidx] = mn * o2;
        }
}

extern "C" void kernel_launch(void* const* d_in, const int* in_sizes, int n_in,
                              void* d_out, int out_size, void* d_ws, size_t ws_size,
                              hipStream_t stream) {
    (void)in_sizes; (void)n_in; (void)out_size;
    const float* x   = (const float*)d_in[0];
    const float* h   = (const float*)d_in[1];
    const float* c   = (const float*)d_in[2];
    const float* m   = (const float*)d_in[3];
    const float* adj = (const float*)d_in[4];
    const float* W   = (const float*)d_in[5];
    const float* bb  = (const float*)d_in[6];
    float* out = (float*)d_out;

    char* ws = (char*)d_ws;
    // tier A (big ws): bf16 adj copy + global_load_lds GEMM; tier B: fp32-staging GEMM
    int haveAdjb = ws_size >= (size_t)(72u << 20);
    uint16_t* adjb = (uint16_t*)ws;                              // 32 MB (tier A)
    size_t pOff = haveAdjb ? (size_t)(32u << 20) : 0;
    uint16_t* P    = (uint16_t*)(ws + pOff);                     // 2 MB phase-1 B (x,h)
    uint16_t* P2   = (uint16_t*)(ws + pOff + (2u << 20));        // 2 MB phase-2 B (h1,m)
    uint16_t* Cbuf = (uint16_t*)(ws + pOff + (4u << 20));        // 2 MB GEMM out (ns==0 only)
    uint16_t* Wp   = (uint16_t*)(ws + pOff + (6u << 20));        // 112 KB packed W (1MB slot)
    size_t partOff = pOff + (7u << 20);
    float* part = (float*)(ws + partOff);

    if (ws_size < (8u << 20)) return;   // harness ws is ~268MB; safety only
    size_t avail = ws_size - partOff;
    int ns = 0;
    if      (avail >= (size_t)(32u << 20)) ns = 8;
    else if (avail >= (size_t)(16u << 20)) ns = 4;
    else if (avail >= (size_t)( 8u << 20)) ns = 2;
    else if (avail >= (size_t)( 4u << 20)) ns = 1;

    const void* Agemm = haveAdjb ? (const void*)adjb : (const void*)adj;
    int isf32A = haveAdjb ? 0 : 1;
    int cvtN = haveAdjb ? 8192 : 0;

    // ONE prep launch: adj->bf16, W pack, x/h -> P, m -> P2 (all input-only)
    prep_kernel<<<cvtN + 112 + 768, 256, 0, stream>>>(adj, adjb, cvtN, W, Wp, x, h, m, P, P2);

    // phase 1: GEMM1 -> part (ax rows 0..127, ah 128..255)
    if (ns) {
        gemm_kernel<<<dim3(32, 2, ns), 256, 0, stream>>>(Agemm, P, part, nullptr, 4096 / ns, 0, isf32A);
    } else {
        gemm_kernel<<<dim3(32, 2, 1), 256, 0, stream>>>(Agemm, P, nullptr, Cbuf, 4096, 1, isf32A);
    }
    // fuse1: 1024 x 1-wave blocks; reduce + dense(MFMA) + GLU + LSTM
    fuse1_kernel<<<1024, 64, 0, stream>>>(part, Cbuf, Wp, bb, c, out + BNF, P2, ns);
    // phase 2: GEMM2 -> part (ah1 rows 0..127, am 128..255)
    if (ns) {
        gemm_kernel<<<dim3(32, 2, ns), 256, 0, stream>>>(Agemm, P2, part, nullptr, 4096 / ns, 0, isf32A);
    } else {
        gemm_kernel<<<dim3(32, 2, 1), 256, 0, stream>>>(Agemm, P2, nullptr, Cbuf, 4096, 1, isf32A);
    }
    fuse2_kernel<<<1024, 64, 0, stream>>>(part, Cbuf, Wp, bb, m, out, out + 2 * BNF, ns);
}

// Round 7
// 187.489 us; speedup vs baseline: 1.0378x; 1.0378x over previous
//
#include <hip/hip_runtime.h>
#include <stdint.h>

typedef __attribute__((ext_vector_type(4))) float f32x4;
typedef __attribute__((ext_vector_type(8))) short s16x8;

#define BB 4
#define NN 4096
#define FF 32
#define BNF (BB*NN*FF)   // 524288

typedef __attribute__((address_space(3))) void       as3_void;
typedef const __attribute__((address_space(1))) void as1_cvoid;

// ---------- bf16 helpers ----------
static __device__ __forceinline__ float bf2f(uint16_t u) {
    union { uint32_t i; float f; } v; v.i = ((uint32_t)u) << 16; return v.f;
}
static __device__ __forceinline__ uint16_t f2bf(float f) {
    union { float f; uint32_t i; } v; v.f = f;
    uint32_t r = v.i + 0x7FFFu + ((v.i >> 16) & 1u);
    return (uint16_t)(r >> 16);
}
static __device__ __forceinline__ float sig_acc(float x) { return 1.0f / (1.0f + expf(-x)); }

// ======================================================================
// prep: ONE launch for all input-only work.  (unchanged)
// ======================================================================
__global__ __launch_bounds__(256) void prep_kernel(
    const float* __restrict__ adj, uint16_t* __restrict__ adjb, int cvtN,
    const float* __restrict__ Wf, uint16_t* __restrict__ Wp,
    const float* __restrict__ x, const float* __restrict__ h,
    const float* __restrict__ m,
    uint16_t* __restrict__ P, uint16_t* __restrict__ P2)
{
    int bid = blockIdx.x;
    int t = threadIdx.x;

    if (bid < cvtN) {
        size_t i = ((size_t)bid * 256 + t) * 8;
        float4 v0 = *(const float4*)(adj + i);
        float4 v1 = *(const float4*)(adj + i + 4);
        union { uint4 u; uint16_t e[8]; } o;
        o.e[0] = f2bf(v0.x); o.e[1] = f2bf(v0.y); o.e[2] = f2bf(v0.z); o.e[3] = f2bf(v0.w);
        o.e[4] = f2bf(v1.x); o.e[5] = f2bf(v1.y); o.e[6] = f2bf(v1.z); o.e[7] = f2bf(v1.w);
        *(uint4*)(adjb + i) = o.u;
        return;
    }
    bid -= cvtN;

    if (bid < 112) {
        // W: fp32 [14][32][64] -> bf16 Wp[gp][col][slot^swz][k&7]
        // B-frag (16x16x32): lane l holds B[k=(l>>4)*8+e][col=l&15].
        int idx = bid * 256 + t;                    // 14*32*64 = 28672
        int g   = idx >> 11;
        int k   = (idx >> 6) & 31;
        int col = idx & 63;
        uint16_t v = f2bf(Wf[idx]);                 // Wf[g][k][col]
        int gp = g >> 1;
        int sl = ((g & 1) << 2) | (k >> 3);
        int ph = sl ^ (col & 7);
        Wp[((gp * 64 + col) * 64) + ph * 8 + (k & 7)] = v;
        return;
    }
    bid -= 112;

    // pack: state [B][N][F] fp32 -> dst[rowbase + b*32 + f][n] bf16
    const float* src; uint16_t* dst; int rowbase, b, n0;
    if (bid < 512) {
        int tensor = bid >> 8;
        src = tensor ? h : x; dst = P; rowbase = tensor * 128;
        b = (bid >> 6) & 3; n0 = (bid & 63) * 64;
    } else {
        int q = bid - 512;
        src = m; dst = P2; rowbase = 128;
        b = q >> 6; n0 = (q & 63) * 64;
    }
    __shared__ uint16_t tl[32][65];
    {
        int i = t >> 2, ch = t & 3;       // node i (0..63), f-chunk ch (8 floats)
        size_t idx = ((size_t)(b * NN + n0 + i)) * FF + ch * 8;
        float4 v0 = *(const float4*)(src + idx);
        float4 v1 = *(const float4*)(src + idx + 4);
        uint16_t e[8] = { f2bf(v0.x), f2bf(v0.y), f2bf(v0.z), f2bf(v0.w),
                          f2bf(v1.x), f2bf(v1.y), f2bf(v1.z), f2bf(v1.w) };
        #pragma unroll
        for (int k = 0; k < 8; k++) tl[ch * 8 + k][i] = e[k];
    }
    __syncthreads();
    {
        int f = t >> 3, ch = t & 7;
        union { uint4 u; uint16_t e[8]; } v;
        #pragma unroll
        for (int k = 0; k < 8; k++) v.e[k] = tl[f][ch * 8 + k];
        size_t row = (size_t)(rowbase + b * 32 + f);
        *(uint4*)(dst + row * NN + n0 + ch * 8) = v.u;
    }
}

// ---------- GEMM (unchanged) ----------
__global__ __launch_bounds__(256) void gemm_kernel(
    const void* __restrict__ Av,      // adj: bf16 (isf32A=0) or fp32 (isf32A=1)
    const uint16_t* __restrict__ Bt,  // [256][4096] bf16
    float* __restrict__ part, uint16_t* __restrict__ Cb,
    int kLen, int direct, int isf32A)
{
    int mt = blockIdx.x, nt = blockIdx.y, ks = blockIdx.z;
    int m0 = mt * 128, c0 = nt * 128, k0 = ks * kLen;
    __shared__ __align__(16) uint16_t aL[128 * 32];
    __shared__ __align__(16) uint16_t bL[128 * 32];
    int t = threadIdx.x;
    int lane = t & 63, w = t >> 6;
    int wm = (w & 1) * 64, wn = (w >> 1) * 64;
    int lm = lane & 15, lk = lane >> 4;

    const uint16_t* A16 = (const uint16_t*)Av;
    const float*    Af  = (const float*)Av;

    f32x4 acc[4][4] = {};

    for (int kk = k0; kk < k0 + kLen; kk += 32) {
        if (!isf32A) {
            #pragma unroll
            for (int q = 0; q < 2; q++) {
                int pos  = q * 4096 + t * 16;            // byte offset into 8KB tile
                int row  = pos >> 6;                     // 64 B per tile row
                int slot = ((pos >> 4) & 3) ^ ((row >> 1) & 3);
                int col  = slot * 8;                     // bf16 element within row
                size_t aidx = (size_t)(m0 + row) * 4096 + kk + col;
                size_t bidx = (size_t)(c0 + row) * 4096 + kk + col;
                __builtin_amdgcn_global_load_lds((as1_cvoid*)(A16 + aidx),
                                                 (as3_void*)((char*)aL + pos), 16, 0, 0);
                __builtin_amdgcn_global_load_lds((as1_cvoid*)(Bt + bidx),
                                                 (as3_void*)((char*)bL + pos), 16, 0, 0);
            }
        } else {
            union { uint4 u; uint16_t e[8]; } sa[2], sb[2];
            #pragma unroll
            for (int q = 0; q < 2; q++) {
                int pos  = q * 4096 + t * 16;
                int row  = pos >> 6;
                int slot = ((pos >> 4) & 3) ^ ((row >> 1) & 3);
                int col  = slot * 8;
                size_t aidx = (size_t)(m0 + row) * 4096 + kk + col;
                size_t bidx = (size_t)(c0 + row) * 4096 + kk + col;
                union { uint4 u[2]; float f[8]; } va;
                va.u[0] = *(const uint4*)(Af + aidx);
                va.u[1] = *(const uint4*)(Af + aidx + 4);
                #pragma unroll
                for (int k = 0; k < 8; k++) sa[q].e[k] = f2bf(va.f[k]);
                sb[q].u = *(const uint4*)(Bt + bidx);
            }
            #pragma unroll
            for (int q = 0; q < 2; q++) {
                int pos = q * 4096 + t * 16;
                *(uint4*)((char*)aL + pos) = sa[q].u;
                *(uint4*)((char*)bL + pos) = sb[q].u;
            }
        }
        __syncthreads();
        s16x8 af[4], bfr[4];
        #pragma unroll
        for (int i = 0; i < 4; i++) {
            int r = wm + i * 16 + lm;
            af[i] = *(const s16x8*)(aL + r * 32 + ((lk ^ ((r >> 1) & 3)) * 8));
        }
        #pragma unroll
        for (int j = 0; j < 4; j++) {
            int r = wn + j * 16 + lm;
            bfr[j] = *(const s16x8*)(bL + r * 32 + ((lk ^ ((r >> 1) & 3)) * 8));
        }
        #pragma unroll
        for (int i = 0; i < 4; i++)
            #pragma unroll
            for (int j = 0; j < 4; j++)
                acc[i][j] = __builtin_amdgcn_mfma_f32_16x16x32_bf16(af[i], bfr[j], acc[i][j], 0, 0, 0);
        __syncthreads();
    }

    // C/D layout: col=lane&15 (c dim), row=(lane>>4)*4+reg (m dim)
    int r4 = (lane >> 4) * 4;
    if (direct) {
        #pragma unroll
        for (int i = 0; i < 4; i++)
            #pragma unroll
            for (int j = 0; j < 4; j++) {
                int c = c0 + wn + j * 16 + lm;
                int mr = m0 + wm + i * 16 + r4;
                union { uint2 u; uint16_t e[4]; } v;
                #pragma unroll
                for (int r = 0; r < 4; r++) v.e[r] = f2bf(acc[i][j][r]);
                *(uint2*)(Cb + (size_t)c * 4096 + mr) = v.u;
            }
    } else {
        #pragma unroll
        for (int i = 0; i < 4; i++)
            #pragma unroll
            for (int j = 0; j < 4; j++) {
                int c = c0 + wn + j * 16 + lm;
                int mr = m0 + wm + i * 16 + r4;
                *(f32x4*)(part + ((size_t)ks * 256 + c) * 4096 + mr) = acc[i][j];
            }
    }
}

// ======================================================================
// fuse1: 1024 blocks x 256 threads (4 waves); block = (batch b, 16 nodes).
// Phase 1: cooperative split-K reduce (thread = (c'-row, 16B chunk), reg dbuf).
// Phase 2: all waves build identical A-frags; wave w computes gate-pair w
//          (B-frags direct from global Wp, L2-broadcast) -> GLU -> SX.
// Phase 3: all 256 threads do the LSTM update from SX; pack h1 -> P2.
// ======================================================================
__global__ __launch_bounds__(256) void fuse1_kernel(
    const float* __restrict__ part,   // [ns][256][4096] fp32 (ns>0)
    const uint16_t* __restrict__ Cbi, // [256][4096] bf16 (ns==0)
    const uint16_t* __restrict__ Wp,  // packed W (prep)
    const float* __restrict__ bf_,
    const float* __restrict__ cf,
    float* __restrict__ cnew, uint16_t* __restrict__ S2t, int ns)
{
    __shared__ float    AL[64 * 17];   // [c'][node 0..15], pitch 17
    __shared__ float    SX[4][64][9];  // per-gate-pair GLU outputs (pad 9)
    __shared__ uint16_t H1[32 * 18];   // [f][node]

    int t = threadIdx.x;
    int bid = blockIdx.x;              // 1024
    int b = bid >> 8, n0 = (bid & 255) * 16;
    int lane = t & 63, w = t >> 6;
    int j = lane & 15, kg = lane >> 4;
    int ej = t & 15, erow = (t >> 4) & 15;   // element coords for phase 3

    // c prefetch for phase 3 (in flight under the reduce)
    float cv[2];
    #pragma unroll
    for (int hh = 0; hh < 2; hh++)
        cv[hh] = cf[((size_t)(b * NN + n0 + erow)) * FF + ej + hh * 16];

    // phase 1: cooperative reduce. thread t -> c'-row r = t>>2, chunk ch = t&3.
    {
        int r = t >> 2, ch = t & 3;
        int crow = (r < 32) ? (b * 32 + r) : (128 + b * 32 + (r - 32));
        if (ns) {
            const float* gp = part + (size_t)crow * 4096 + n0 + ch * 4;
            f32x4 cur = *(const f32x4*)gp;
            f32x4 sum = {};
            for (int ks = 0; ks < ns; ks++) {
                f32x4 nxt;
                if (ks + 1 < ns) nxt = *(const f32x4*)(gp + (size_t)(ks + 1) * (256 * 4096));
                sum += cur;
                if (ks + 1 < ns) cur = nxt;
            }
            #pragma unroll
            for (int e = 0; e < 4; e++) AL[r * 17 + ch * 4 + e] = sum[e];
        } else {
            const uint16_t* cp = Cbi + (size_t)crow * 4096 + n0 + ch * 4;
            uint2 v = *(const uint2*)cp;
            const uint16_t* pe = (const uint16_t*)&v;
            #pragma unroll
            for (int e = 0; e < 4; e++) AL[r * 17 + ch * 4 + e] = bf2f(pe[e]);
        }
    }
    __syncthreads();

    // phase 2: A frags (identical in every wave); wave w = gate-pair w
    s16x8 a_ax, a_ah;
    #pragma unroll
    for (int e = 0; e < 8; e++) {
        int k = kg * 8 + e;
        a_ax[e] = (short)f2bf(AL[k * 17 + j]);
        a_ah[e] = (short)f2bf(AL[(32 + k) * 17 + j]);
    }
    {
        int p = w;                                // gate-pair: even=ax, odd=ah
        int g0 = p * 2, g1 = p * 2 + 1;
        f32x4 ac0[4] = {}, ac1[4] = {};
        #pragma unroll
        for (int ct = 0; ct < 4; ct++) {
            int col = ct * 16 + j;
            int ph0 = (kg)     ^ (col & 7);
            int ph1 = (4 + kg) ^ (col & 7);
            s16x8 b0 = *(const s16x8*)(Wp + (p * 64 + col) * 64 + ph0 * 8);
            s16x8 b1 = *(const s16x8*)(Wp + (p * 64 + col) * 64 + ph1 * 8);
            ac0[ct] = __builtin_amdgcn_mfma_f32_16x16x32_bf16(a_ax, b0, ac0[ct], 0, 0, 0);
            ac1[ct] = __builtin_amdgcn_mfma_f32_16x16x32_bf16(a_ah, b1, ac1[ct], 0, 0, 0);
        }
        #pragma unroll
        for (int hh = 0; hh < 2; hh++)
            #pragma unroll
            for (int r = 0; r < 4; r++) {
                float z0l = ac0[hh][r]     + bf_[g0 * 64 + hh * 16 + j];
                float z0r = ac0[2 + hh][r] + bf_[g0 * 64 + 32 + hh * 16 + j];
                float z1l = ac1[hh][r]     + bf_[g1 * 64 + hh * 16 + j];
                float z1r = ac1[2 + hh][r] + bf_[g1 * 64 + 32 + hh * 16 + j];
                SX[p][lane][hh * 4 + r] = z0l * sig_acc(z0r) + z1l * sig_acc(z1r);
            }
    }
    __syncthreads();

    // phase 3: LSTM update; thread t handles element (erow, ej), hh=0,1
    {
        int pl = ((erow >> 2) << 4) | ej;         // producer lane
        int ridx = erow & 3;
        #pragma unroll
        for (int hh = 0; hh < 2; hh++) {
            float s0 = SX[0][pl][hh * 4 + ridx];
            float s1 = SX[1][pl][hh * 4 + ridx];
            float s2 = SX[2][pl][hh * 4 + ridx];
            float s3 = SX[3][pl][hh * 4 + ridx];
            float fg = sig_acc(s0), ig = sig_acc(s1);
            float cc = tanhf(s2),   og = sig_acc(s3);
            float cn = fg * cv[hh] + ig * cc;
            size_t gidx = ((size_t)(b * NN + n0 + erow)) * FF + ej + hh * 16;
            cnew[gidx] = cn;
            H1[(ej + hh * 16) * 18 + erow] = f2bf(og * tanhf(cn));
        }
    }
    __syncthreads();
    if (t < 64) {   // pack h1 -> P2 rows b*32+f (GEMM2 B operand, rows 0..127)
        int f = t >> 1, half = t & 1;
        union { uint4 u; uint16_t e[8]; } v;
        #pragma unroll
        for (int k = 0; k < 8; k++) v.e[k] = H1[f * 18 + half * 8 + k];
        *(uint4*)(S2t + ((size_t)(b * 32 + f)) * NN + n0 + half * 8) = v.u;
    }
}

// ======================================================================
// fuse2: same structure, 3 gate-pairs (waves 0..2; wave 3 idles in phase 2).
// ======================================================================
__global__ __launch_bounds__(256) void fuse2_kernel(
    const float* __restrict__ part,
    const uint16_t* __restrict__ Cbi,
    const uint16_t* __restrict__ Wp,
    const float* __restrict__ bf_,
    const float* __restrict__ mf,
    float* __restrict__ hnew, float* __restrict__ mnew, int ns)
{
    __shared__ float AL[64 * 17];
    __shared__ float SX[3][64][9];

    int t = threadIdx.x;
    int bid = blockIdx.x;
    int b = bid >> 8, n0 = (bid & 255) * 16;
    int lane = t & 63, w = t >> 6;
    int j = lane & 15, kg = lane >> 4;
    int ej = t & 15, erow = (t >> 4) & 15;

    float mv[2];
    #pragma unroll
    for (int hh = 0; hh < 2; hh++)
        mv[hh] = mf[((size_t)(b * NN + n0 + erow)) * FF + ej + hh * 16];

    {
        int r = t >> 2, ch = t & 3;
        int crow = (r < 32) ? (b * 32 + r) : (128 + b * 32 + (r - 32));
        if (ns) {
            const float* gp = part + (size_t)crow * 4096 + n0 + ch * 4;
            f32x4 cur = *(const f32x4*)gp;
            f32x4 sum = {};
            for (int ks = 0; ks < ns; ks++) {
                f32x4 nxt;
                if (ks + 1 < ns) nxt = *(const f32x4*)(gp + (size_t)(ks + 1) * (256 * 4096));
                sum += cur;
                if (ks + 1 < ns) cur = nxt;
            }
            #pragma unroll
            for (int e = 0; e < 4; e++) AL[r * 17 + ch * 4 + e] = sum[e];
        } else {
            const uint16_t* cp = Cbi + (size_t)crow * 4096 + n0 + ch * 4;
            uint2 v = *(const uint2*)cp;
            const uint16_t* pe = (const uint16_t*)&v;
            #pragma unroll
            for (int e = 0; e < 4; e++) AL[r * 17 + ch * 4 + e] = bf2f(pe[e]);
        }
    }
    __syncthreads();

    if (w < 3) {
        s16x8 a_h1, a_m;
        #pragma unroll
        for (int e = 0; e < 8; e++) {
            int k = kg * 8 + e;
            a_h1[e] = (short)f2bf(AL[k * 17 + j]);
            a_m[e]  = (short)f2bf(AL[(32 + k) * 17 + j]);
        }
        const uint16_t* WpG = Wp + 4 * 64 * 64;   // gate-pairs 4..6 (gates 8..13)
        const float*    bG  = bf_ + 512;
        int p = w;
        int g0 = p * 2, g1 = p * 2 + 1;           // even: ah1, odd: am
        f32x4 ac0[4] = {}, ac1[4] = {};
        #pragma unroll
        for (int ct = 0; ct < 4; ct++) {
            int col = ct * 16 + j;
            int ph0 = (kg)     ^ (col & 7);
            int ph1 = (4 + kg) ^ (col & 7);
            s16x8 b0 = *(const s16x8*)(WpG + (p * 64 + col) * 64 + ph0 * 8);
            s16x8 b1 = *(const s16x8*)(WpG + (p * 64 + col) * 64 + ph1 * 8);
            ac0[ct] = __builtin_amdgcn_mfma_f32_16x16x32_bf16(a_h1, b0, ac0[ct], 0, 0, 0);
            ac1[ct] = __builtin_amdgcn_mfma_f32_16x16x32_bf16(a_m, b1, ac1[ct], 0, 0, 0);
        }
        #pragma unroll
        for (int hh = 0; hh < 2; hh++)
            #pragma unroll
            for (int r = 0; r < 4; r++) {
                float z0l = ac0[hh][r]     + bG[g0 * 64 + hh * 16 + j];
                float z0r = ac0[2 + hh][r] + bG[g0 * 64 + 32 + hh * 16 + j];
                float z1l = ac1[hh][r]     + bG[g1 * 64 + hh * 16 + j];
                float z1r = ac1[2 + hh][r] + bG[g1 * 64 + 32 + hh * 16 + j];
                SX[p][lane][hh * 4 + r] = z0l * sig_acc(z0r) + z1l * sig_acc(z1r);
            }
    }
    __syncthreads();

    {
        int pl = ((erow >> 2) << 4) | ej;
        int ridx = erow & 3;
        #pragma unroll
        for (int hh = 0; hh < 2; hh++) {
            float s0 = SX[0][pl][hh * 4 + ridx];
            float s1 = SX[1][pl][hh * 4 + ridx];
            float s2 = SX[2][pl][hh * 4 + ridx];
            float i2 = sig_acc(s0);
            float gg = sig_acc(s1);
            float o2 = sig_acc(s2);
            float mn = i2 * mv[hh] + (1.0f - i2) * gg;
            size_t gidx = ((size_t)(b * NN + n0 + erow)) * FF + ej + hh * 16;
            mnew[gidx] = mn;
            hnew[gidx] = mn * o2;
        }
    }
}

extern "C" void kernel_launch(void* const* d_in, const int* in_sizes, int n_in,
                              void* d_out, int out_size, void* d_ws, size_t ws_size,
                              hipStream_t stream) {
    (void)in_sizes; (void)n_in; (void)out_size;
    const float* x   = (const float*)d_in[0];
    const float* h   = (const float*)d_in[1];
    const float* c   = (const float*)d_in[2];
    const float* m   = (const float*)d_in[3];
    const float* adj = (const float*)d_in[4];
    const float* W   = (const float*)d_in[5];
    const float* bb  = (const float*)d_in[6];
    float* out = (float*)d_out;

    char* ws = (char*)d_ws;
    // tier A (big ws): bf16 adj copy + global_load_lds GEMM; tier B: fp32-staging GEMM
    int haveAdjb = ws_size >= (size_t)(72u << 20);
    uint16_t* adjb = (uint16_t*)ws;                              // 32 MB (tier A)
    size_t pOff = haveAdjb ? (size_t)(32u << 20) : 0;
    uint16_t* P    = (uint16_t*)(ws + pOff);                     // 2 MB phase-1 B (x,h)
    uint16_t* P2   = (uint16_t*)(ws + pOff + (2u << 20));        // 2 MB phase-2 B (h1,m)
    uint16_t* Cbuf = (uint16_t*)(ws + pOff + (4u << 20));        // 2 MB GEMM out (ns==0 only)
    uint16_t* Wp   = (uint16_t*)(ws + pOff + (6u << 20));        // 112 KB packed W (1MB slot)
    size_t partOff = pOff + (7u << 20);
    float* part = (float*)(ws + partOff);

    if (ws_size < (8u << 20)) return;   // harness ws is ~268MB; safety only
    size_t avail = ws_size - partOff;
    int ns = 0;
    if      (avail >= (size_t)(32u << 20)) ns = 8;
    else if (avail >= (size_t)(16u << 20)) ns = 4;
    else if (avail >= (size_t)( 8u << 20)) ns = 2;
    else if (avail >= (size_t)( 4u << 20)) ns = 1;

    const void* Agemm = haveAdjb ? (const void*)adjb : (const void*)adj;
    int isf32A = haveAdjb ? 0 : 1;
    int cvtN = haveAdjb ? 8192 : 0;

    // ONE prep launch: adj->bf16, W pack, x/h -> P, m -> P2 (all input-only)
    prep_kernel<<<cvtN + 112 + 768, 256, 0, stream>>>(adj, adjb, cvtN, W, Wp, x, h, m, P, P2);

    // phase 1: GEMM1 -> part (ax rows 0..127, ah 128..255)
    if (ns) {
        gemm_kernel<<<dim3(32, 2, ns), 256, 0, stream>>>(Agemm, P, part, nullptr, 4096 / ns, 0, isf32A);
    } else {
        gemm_kernel<<<dim3(32, 2, 1), 256, 0, stream>>>(Agemm, P, nullptr, Cbuf, 4096, 1, isf32A);
    }
    // fuse1: 1024 x 4-wave blocks; coop reduce + gate-split MFMA + LSTM
    fuse1_kernel<<<1024, 256, 0, stream>>>(part, Cbuf, Wp, bb, c, out + BNF, P2, ns);
    // phase 2: GEMM2 -> part (ah1 rows 0..127, am 128..255)
    if (ns) {
        gemm_kernel<<<dim3(32, 2, ns), 256, 0, stream>>>(Agemm, P2, part, nullptr, 4096 / ns, 0, isf32A);
    } else {
        gemm_kernel<<<dim3(32, 2, 1), 256, 0, stream>>>(Agemm, P2, nullptr, Cbuf, 4096, 1, isf32A);
    }
    fuse2_kernel<<<1024, 256, 0, stream>>>(part, Cbuf, Wp, bb, m, out, out + 2 * BNF, ns);
}